// Round 1
// 319.429 us; speedup vs baseline: 1.0102x; 1.0102x over previous
//
#include <hip/hip_runtime.h>

#define N_NODES 100000
#define N_EDGES 1600000
#define IN_CH   128
#define HEADS   4
#define OUT_CH  32
#define HID     128   // HEADS*OUT_CH
#define NEG_SLOPE 0.2f

#define BNODES  1024                      // nodes per bucket (pow2)
#define NBUCK   ((N_NODES + BNODES - 1) / BNODES)   // 98
#define NBLK    256                       // histogram / scatter blocks
#define EPB     (N_EDGES / NBLK)          // 6250 edges per block (exact)

typedef unsigned int  uint;
typedef unsigned short ushort;

// bf16 round-to-nearest-even pack
__device__ __forceinline__ ushort f2bf(float f) {
    uint u = __float_as_uint(f);
    return (ushort)((u + 0x7FFFu + ((u >> 16) & 1u)) >> 16);
}

// ---------------- K1: h = x @ W  (fp32 compute, bf16 store) ----------------
#define BM 64
#define BK 32
__global__ __launch_bounds__(256) void k_gemm(const float* __restrict__ x,
                                              const float* __restrict__ w,
                                              ushort* __restrict__ h) {
    __shared__ float xs[BK][BM + 4];
    __shared__ float wsld[BK][HID + 4];

    const int tid  = threadIdx.x;
    const int nodeBase = blockIdx.x * BM;
    const int c0 = (tid & 15) * 8;
    const int n0 = (tid >> 4) * 4;

    float acc[4][8];
#pragma unroll
    for (int i = 0; i < 4; i++)
#pragma unroll
        for (int j = 0; j < 8; j++) acc[i][j] = 0.0f;

    for (int k0 = 0; k0 < IN_CH; k0 += BK) {
#pragma unroll
        for (int l = 0; l < 2; l++) {
            int idx  = tid + l * 256;
            int row  = idx >> 3;
            int col4 = (idx & 7) * 4;
            int n = nodeBase + row;
            float4 v = make_float4(0.f, 0.f, 0.f, 0.f);
            if (n < N_NODES) v = *reinterpret_cast<const float4*>(x + (size_t)n * IN_CH + k0 + col4);
            xs[col4 + 0][row] = v.x;
            xs[col4 + 1][row] = v.y;
            xs[col4 + 2][row] = v.z;
            xs[col4 + 3][row] = v.w;
        }
#pragma unroll
        for (int l = 0; l < 4; l++) {
            int idx  = tid + l * 256;
            int row  = idx >> 5;
            int col4 = (idx & 31) * 4;
            float4 v = *reinterpret_cast<const float4*>(w + (size_t)(k0 + row) * HID + col4);
            *reinterpret_cast<float4*>(&wsld[row][col4]) = v;
        }
        __syncthreads();

#pragma unroll
        for (int kk = 0; kk < BK; kk++) {
            float4 xv = *reinterpret_cast<const float4*>(&xs[kk][n0]);
            float4 wa = *reinterpret_cast<const float4*>(&wsld[kk][c0]);
            float4 wb = *reinterpret_cast<const float4*>(&wsld[kk][c0 + 4]);
            float xr[4] = {xv.x, xv.y, xv.z, xv.w};
            float wr[8] = {wa.x, wa.y, wa.z, wa.w, wb.x, wb.y, wb.z, wb.w};
#pragma unroll
            for (int i = 0; i < 4; i++)
#pragma unroll
                for (int j = 0; j < 8; j++)
                    acc[i][j] = fmaf(xr[i], wr[j], acc[i][j]);
        }
        __syncthreads();
    }

#pragma unroll
    for (int i = 0; i < 4; i++) {
        int n = nodeBase + n0 + i;
        if (n < N_NODES) {
            uint4 pk;
            pk.x = (uint)f2bf(acc[i][0]) | ((uint)f2bf(acc[i][1]) << 16);
            pk.y = (uint)f2bf(acc[i][2]) | ((uint)f2bf(acc[i][3]) << 16);
            pk.z = (uint)f2bf(acc[i][4]) | ((uint)f2bf(acc[i][5]) << 16);
            pk.w = (uint)f2bf(acc[i][6]) | ((uint)f2bf(acc[i][7]) << 16);
            *reinterpret_cast<uint4*>(h + (size_t)n * HID + c0) = pk;
        }
    }
}

// ---------------- K2: per-(node,head) attention scores (bf16 h) ----------------
__global__ void k_scores(const ushort* __restrict__ h, const float* __restrict__ att,
                         float* __restrict__ s_src, float* __restrict__ s_dst) {
    int i = blockIdx.x * blockDim.x + threadIdx.x;   // i = n*HEADS + head
    if (i >= N_NODES * HEADS) return;
    int head = i & (HEADS - 1);
    const uint* hp = reinterpret_cast<const uint*>(h + (size_t)i * OUT_CH);  // 16 uints
    const float* as = att + head * (2 * OUT_CH);
    const float* ad = as + OUT_CH;
    float ss = 0.f, sd = 0.f;
#pragma unroll
    for (int q = 0; q < 4; q++) {
        uint4 u = reinterpret_cast<const uint4*>(hp)[q];
        uint uv[4] = {u.x, u.y, u.z, u.w};
#pragma unroll
        for (int t = 0; t < 4; t++) {
            int c = q * 8 + t * 2;
            float f0 = __uint_as_float(uv[t] << 16);
            float f1 = __uint_as_float(uv[t] & 0xFFFF0000u);
            ss += f0 * as[c] + f1 * as[c + 1];
            sd += f0 * ad[c] + f1 * ad[c + 1];
        }
    }
    s_src[i] = ss;
    s_dst[i] = sd;
}

// ---------------- CSR build, level 1a: per-block bucket histogram ----------------
__global__ __launch_bounds__(256) void k_h0(const int* __restrict__ ei,
                                            int* __restrict__ hist) {
    __shared__ int cnt[NBUCK];
    int t = threadIdx.x;
    if (t < NBUCK) cnt[t] = 0;
    __syncthreads();
    int base = blockIdx.x * EPB;
    for (int e = base + t; e < base + EPB; e += 256)
        atomicAdd(&cnt[ei[N_EDGES + e] >> 10], 1);
    __syncthreads();
    if (t < NBUCK) hist[blockIdx.x * NBUCK + t] = cnt[t];
}

// ---------------- CSR build, level 1b: bucket bases + per-(block,bucket) bases ----------------
__global__ __launch_bounds__(128) void k_sc0(int* __restrict__ hist,
                                             int* __restrict__ bucket_base) {
    __shared__ int sm[128];
    int t = threadIdx.x;
    int total = 0;
    if (t < NBUCK) {
#pragma unroll 8
        for (int r = 0; r < NBLK; r++) total += hist[r * NBUCK + t];
    }
    sm[t] = total;
    __syncthreads();
    for (int off = 1; off < 128; off <<= 1) {
        int v = (t >= off) ? sm[t - off] : 0;
        __syncthreads();
        sm[t] += v;
        __syncthreads();
    }
    int excl = sm[t] - total;
    if (t < NBUCK) {
        bucket_base[t] = excl;
        int running = excl;
#pragma unroll 8
        for (int r = 0; r < NBLK; r++) {
            int tmp = hist[r * NBUCK + t];
            hist[r * NBUCK + t] = running;
            running += tmp;
        }
    }
    if (t == 0) bucket_base[NBUCK] = N_EDGES;
}

// ---------------- CSR build, level 1c: scatter into bucket-sorted packed array ----------------
__global__ __launch_bounds__(256) void k_b1(const int* __restrict__ ei,
                                            const int* __restrict__ hist,
                                            int* __restrict__ packed) {
    __shared__ int cur[NBUCK];
    int t = threadIdx.x;
    if (t < NBUCK) cur[t] = hist[blockIdx.x * NBUCK + t];
    __syncthreads();
    int base = blockIdx.x * EPB;
    for (int e = base + t; e < base + EPB; e += 256) {
        int src = ei[e], dst = ei[N_EDGES + e];
        int pos = atomicAdd(&cur[dst >> 10], 1);
        packed[pos] = (src << 10) | (dst & (BNODES - 1));   // src<2^17, fits
    }
}

// ---------------- CSR build, level 2: per-bucket exact CSR + row_start ----------------
__global__ __launch_bounds__(256) void k_b2(const int* __restrict__ packed,
                                            const int* __restrict__ bucket_base,
                                            int* __restrict__ csr_src,
                                            int* __restrict__ row_start) {
    __shared__ int cnt[BNODES];
    __shared__ int cur[BNODES];
    __shared__ int sm[256];
    int b = blockIdx.x, t = threadIdx.x;
    int beg = bucket_base[b], end = bucket_base[b + 1];
#pragma unroll
    for (int j = 0; j < 4; j++) cnt[t * 4 + j] = 0;
    __syncthreads();
    for (int e = beg + t; e < end; e += 256)
        atomicAdd(&cnt[packed[e] & (BNODES - 1)], 1);
    __syncthreads();
    int c0 = cnt[t * 4], c1 = cnt[t * 4 + 1], c2 = cnt[t * 4 + 2], c3 = cnt[t * 4 + 3];
    int tot = c0 + c1 + c2 + c3;
    sm[t] = tot;
    __syncthreads();
    for (int off = 1; off < 256; off <<= 1) {
        int v = (t >= off) ? sm[t - off] : 0;
        __syncthreads();
        sm[t] += v;
        __syncthreads();
    }
    int p0 = beg + sm[t] - tot;
    int p1 = p0 + c0, p2 = p1 + c1, p3 = p2 + c2;
    cur[t * 4] = p0; cur[t * 4 + 1] = p1; cur[t * 4 + 2] = p2; cur[t * 4 + 3] = p3;
    int nodeb = b * BNODES + t * 4;
    int pv[4] = {p0, p1, p2, p3};
#pragma unroll
    for (int j = 0; j < 4; j++)
        if (nodeb + j <= N_NODES) row_start[nodeb + j] = pv[j];
    __syncthreads();
    for (int e = beg + t; e < end; e += 256) {
        int pk = packed[e];
        int pos = atomicAdd(&cur[pk & (BNODES - 1)], 1);
        csr_src[pos] = pk >> 10;
    }
}

// ---------------- K5: gather aggregation — one wave per node, 4 edges per iter ----------------
// Lane split: g = lane>>4 selects one of 4 concurrent edges; q = lane&15 selects
// an 8-channel quad (16B uint4 of bf16). One dwordx4 wave-load covers 4 edge rows
// (vs 4 dword wave-loads before), and the per-edge scalar chain (score lookup,
// leaky-ReLU, expf) runs on 16 lanes instead of 64. Epilogue tree-reduces the
// 4 edge-groups with shfl_xor(16/32).
__global__ __launch_bounds__(256) void k_agg(const int* __restrict__ row_start,
                                             const int* __restrict__ csr_src,
                                             const float* __restrict__ s_src,
                                             const float* __restrict__ s_dst,
                                             const ushort* __restrict__ h,
                                             const float* __restrict__ bias,
                                             float* __restrict__ out) {
    const int n    = blockIdx.x * 4 + (threadIdx.x >> 6);   // 4 nodes per block, 1 wave each
    const int lane = threadIdx.x & 63;
    const int g    = lane >> 4;          // edge sub-group 0..3
    const int q    = lane & 15;          // channel quad: ch = q*8 .. q*8+7
    const int head = q >> 2;             // 32 ch per head / 8 ch per quad

    const float sdh = s_dst[n * HEADS + head];
    const int beg = row_start[n], end = row_start[n + 1];
    const uint4* __restrict__ hrow = reinterpret_cast<const uint4*>(h);   // 16 uint4 per node row

    float acc[8];
#pragma unroll
    for (int k = 0; k < 8; k++) acc[k] = 0.f;
    float sum_w = 0.f;

#pragma unroll 2
    for (int j = beg; j < end; j += 4) {
        int e = j + g;
        bool valid = e < end;
        int src = csr_src[valid ? e : end - 1];          // clamp keeps load safe
        float ss = s_src[src * HEADS + head];            // L2-resident table
        uint4 u = hrow[(size_t)src * (HID / 8) + q];     // 16B = 8 bf16 channels
        float a = ss + sdh;
        a = fmaxf(a, NEG_SLOPE * a);                     // leaky relu
        float wgt = valid ? __expf(a) : 0.f;
        sum_w += wgt;
        uint uv[4] = {u.x, u.y, u.z, u.w};
#pragma unroll
        for (int t = 0; t < 4; t++) {
            acc[2 * t]     = fmaf(wgt, __uint_as_float(uv[t] << 16),        acc[2 * t]);
            acc[2 * t + 1] = fmaf(wgt, __uint_as_float(uv[t] & 0xFFFF0000u), acc[2 * t + 1]);
        }
    }

    // reduce the 4 edge-groups (lanes differing in bits 4,5)
#pragma unroll
    for (int k = 0; k < 8; k++) {
        acc[k] += __shfl_xor(acc[k], 16);
        acc[k] += __shfl_xor(acc[k], 32);
    }
    sum_w += __shfl_xor(sum_w, 16);
    sum_w += __shfl_xor(sum_w, 32);

    if (g == 0) {
        float inv = 1.0f / (sum_w + 1e-16f);
        int ch = q * 8;
        float4 b0 = *reinterpret_cast<const float4*>(bias + ch);
        float4 b1 = *reinterpret_cast<const float4*>(bias + ch + 4);
        float4 o0, o1;
        o0.x = acc[0] * inv + b0.x; o0.y = acc[1] * inv + b0.y;
        o0.z = acc[2] * inv + b0.z; o0.w = acc[3] * inv + b0.w;
        o1.x = acc[4] * inv + b1.x; o1.y = acc[5] * inv + b1.y;
        o1.z = acc[6] * inv + b1.z; o1.w = acc[7] * inv + b1.w;
        *reinterpret_cast<float4*>(out + (size_t)n * HID + ch)     = o0;
        *reinterpret_cast<float4*>(out + (size_t)n * HID + ch + 4) = o1;
    }
}

extern "C" void kernel_launch(void* const* d_in, const int* in_sizes, int n_in,
                              void* d_out, int out_size, void* d_ws, size_t ws_size,
                              hipStream_t stream) {
    const float* x    = (const float*)d_in[0];
    const int*   ei   = (const int*)  d_in[1];
    const float* w    = (const float*)d_in[2];
    const float* att  = (const float*)d_in[3];
    const float* bias = (const float*)d_in[4];
    float* out = (float*)d_out;

    char* p = (char*)d_ws;
    float* s_src    = (float*)p;  p += (size_t)N_NODES * HEADS * 4;   // 1.6 MB
    float* s_dst    = (float*)p;  p += (size_t)N_NODES * HEADS * 4;   // 1.6 MB
    ushort* h       = (ushort*)p; p += (size_t)N_NODES * HID * 2;     // 25.6 MB (16B-aligned)
    int* csr_src    = (int*)p;    p += (size_t)N_EDGES * 4;           // 6.4 MB
    int* packed     = (int*)p;    p += (size_t)N_EDGES * 4;           // 6.4 MB
    int* hist       = (int*)p;    p += (size_t)NBLK * NBUCK * 4;      // 100 KB
    int* row_start  = (int*)p;    p += (size_t)(N_NODES + 1) * 4;
    int* bucket_base= (int*)p;    p += (size_t)(NBUCK + 1) * 4;

    k_gemm<<<(N_NODES + BM - 1) / BM, 256, 0, stream>>>(x, w, h);
    k_scores<<<(N_NODES * HEADS + 255) / 256, 256, 0, stream>>>(h, att, s_src, s_dst);
    k_h0<<<NBLK, 256, 0, stream>>>(ei, hist);
    k_sc0<<<1, 128, 0, stream>>>(hist, bucket_base);
    k_b1<<<NBLK, 256, 0, stream>>>(ei, hist, packed);
    k_b2<<<NBUCK, 256, 0, stream>>>(packed, bucket_base, csr_src, row_start);
    k_agg<<<N_NODES / 4, 256, 0, stream>>>(row_start, csr_src, s_src, s_dst, h, bias, out);
}

// Round 2
// 301.800 us; speedup vs baseline: 1.0692x; 1.0584x over previous
//
#include <hip/hip_runtime.h>

#define N_NODES 100000
#define N_EDGES 1600000
#define IN_CH   128
#define HEADS   4
#define OUT_CH  32
#define HID     128   // HEADS*OUT_CH
#define NEG_SLOPE 0.2f

#define BNODES  1024                      // nodes per bucket (pow2)
#define NBUCK   ((N_NODES + BNODES - 1) / BNODES)   // 98
#define NBLK    256                       // scatter blocks
#define EPB     (N_EDGES / NBLK)          // 6250 edges per block (exact)
#define BSLOT   18432                     // padded slots per bucket (mean 16384, +16 sigma)

typedef unsigned int  uint;
typedef unsigned short ushort;

// bf16 round-to-nearest-even pack
__device__ __forceinline__ ushort f2bf(float f) {
    uint u = __float_as_uint(f);
    return (ushort)((u + 0x7FFFu + ((u >> 16) & 1u)) >> 16);
}

// ---------------- K1: h = x @ W (fp32 compute, bf16 store) + fused attention scores ----
// Epilogue computes s_src/s_dst per (node,head) from the in-register acc tile:
// thread holds channels c0..c0+7 (all one head); shfl_xor(1,2) reduces the 4
// threads covering the head's 32 channels. Saves the separate k_scores pass over h.
#define BM 64
#define BK 32
__global__ __launch_bounds__(256) void k_gemm(const float* __restrict__ x,
                                              const float* __restrict__ w,
                                              const float* __restrict__ att,
                                              ushort* __restrict__ h,
                                              float* __restrict__ s_src,
                                              float* __restrict__ s_dst,
                                              int* __restrict__ bucket_cnt) {
    __shared__ float xs[BK][BM + 4];
    __shared__ float wsld[BK][HID + 4];

    const int tid  = threadIdx.x;
    const int nodeBase = blockIdx.x * BM;
    const int c0 = (tid & 15) * 8;
    const int n0 = (tid >> 4) * 4;

    // zero the bucket reservation counters for this iteration (k_scatter runs after us)
    if (blockIdx.x == 0 && tid < NBUCK) bucket_cnt[tid] = 0;

    float acc[4][8];
#pragma unroll
    for (int i = 0; i < 4; i++)
#pragma unroll
        for (int j = 0; j < 8; j++) acc[i][j] = 0.0f;

    for (int k0 = 0; k0 < IN_CH; k0 += BK) {
#pragma unroll
        for (int l = 0; l < 2; l++) {
            int idx  = tid + l * 256;
            int row  = idx >> 3;
            int col4 = (idx & 7) * 4;
            int n = nodeBase + row;
            float4 v = make_float4(0.f, 0.f, 0.f, 0.f);
            if (n < N_NODES) v = *reinterpret_cast<const float4*>(x + (size_t)n * IN_CH + k0 + col4);
            xs[col4 + 0][row] = v.x;
            xs[col4 + 1][row] = v.y;
            xs[col4 + 2][row] = v.z;
            xs[col4 + 3][row] = v.w;
        }
#pragma unroll
        for (int l = 0; l < 4; l++) {
            int idx  = tid + l * 256;
            int row  = idx >> 5;
            int col4 = (idx & 31) * 4;
            float4 v = *reinterpret_cast<const float4*>(w + (size_t)(k0 + row) * HID + col4);
            *reinterpret_cast<float4*>(&wsld[row][col4]) = v;
        }
        __syncthreads();

#pragma unroll
        for (int kk = 0; kk < BK; kk++) {
            float4 xv = *reinterpret_cast<const float4*>(&xs[kk][n0]);
            float4 wa = *reinterpret_cast<const float4*>(&wsld[kk][c0]);
            float4 wb = *reinterpret_cast<const float4*>(&wsld[kk][c0 + 4]);
            float xr[4] = {xv.x, xv.y, xv.z, xv.w};
            float wr[8] = {wa.x, wa.y, wa.z, wa.w, wb.x, wb.y, wb.z, wb.w};
#pragma unroll
            for (int i = 0; i < 4; i++)
#pragma unroll
                for (int j = 0; j < 8; j++)
                    acc[i][j] = fmaf(xr[i], wr[j], acc[i][j]);
        }
        __syncthreads();
    }

    // h store (bf16)
#pragma unroll
    for (int i = 0; i < 4; i++) {
        int n = nodeBase + n0 + i;
        if (n < N_NODES) {
            uint4 pk;
            pk.x = (uint)f2bf(acc[i][0]) | ((uint)f2bf(acc[i][1]) << 16);
            pk.y = (uint)f2bf(acc[i][2]) | ((uint)f2bf(acc[i][3]) << 16);
            pk.z = (uint)f2bf(acc[i][4]) | ((uint)f2bf(acc[i][5]) << 16);
            pk.w = (uint)f2bf(acc[i][6]) | ((uint)f2bf(acc[i][7]) << 16);
            *reinterpret_cast<uint4*>(h + (size_t)n * HID + c0) = pk;
        }
    }

    // fused attention scores: channels c0..c0+7 all belong to head c0>>5
    {
        const int head = c0 >> 5;
        const int cb   = c0 & 31;                       // channel offset within head
        const float* as = att + head * (2 * OUT_CH) + cb;
        const float* ad = as + OUT_CH;
        float av[8], dv[8];
#pragma unroll
        for (int j = 0; j < 8; j++) { av[j] = as[j]; dv[j] = ad[j]; }
#pragma unroll
        for (int i = 0; i < 4; i++) {
            float ps = 0.f, pd = 0.f;
#pragma unroll
            for (int j = 0; j < 8; j++) {
                ps = fmaf(acc[i][j], av[j], ps);
                pd = fmaf(acc[i][j], dv[j], pd);
            }
            // reduce across the 4 threads (tid bits 0,1) sharing this (node,head)
            ps += __shfl_xor(ps, 1);  ps += __shfl_xor(ps, 2);
            pd += __shfl_xor(pd, 1);  pd += __shfl_xor(pd, 2);
            int n = nodeBase + n0 + i;
            if ((tid & 3) == 0 && n < N_NODES) {
                s_src[n * HEADS + head] = ps;
                s_dst[n * HEADS + head] = pd;
            }
        }
    }
}

// ---------------- CSR build, stage 1: single-kernel bucket scatter ----------------
// Per block: LDS histogram of its 6250 edges -> one global atomicAdd per bucket to
// reserve a range inside that bucket's fixed padded region -> scatter. Order within
// a bucket is irrelevant (k_b2 re-sorts by node), so no global prefix-scan / no
// separate histogram + serial-scan kernels.
__global__ __launch_bounds__(256) void k_scatter(const int* __restrict__ ei,
                                                 int* __restrict__ bucket_cnt,
                                                 int* __restrict__ packed) {
    __shared__ int cnt[NBUCK];
    __shared__ int cur[NBUCK];
    int t = threadIdx.x;
    if (t < NBUCK) cnt[t] = 0;
    __syncthreads();
    int base = blockIdx.x * EPB;
    for (int e = base + t; e < base + EPB; e += 256)
        atomicAdd(&cnt[ei[N_EDGES + e] >> 10], 1);
    __syncthreads();
    if (t < NBUCK) {
        int myBase = atomicAdd(&bucket_cnt[t], cnt[t]);   // device-scope reservation
        cur[t] = t * BSLOT + myBase;
    }
    __syncthreads();
    for (int e = base + t; e < base + EPB; e += 256) {
        int src = ei[e], dst = ei[N_EDGES + e];
        int pos = atomicAdd(&cur[dst >> 10], 1);
        packed[pos] = (src << 10) | (dst & (BNODES - 1));   // src<2^17, fits
    }
}

// ---------------- CSR build, stage 2: per-bucket exact CSR + row_start ----------------
// Reads the padded bucket region, writes TIGHT csr_src/row_start (tight base from a
// 98-element scan of bucket_cnt), so k_agg is unchanged.
__global__ __launch_bounds__(256) void k_b2(const int* __restrict__ packed,
                                            const int* __restrict__ bucket_cnt,
                                            int* __restrict__ csr_src,
                                            int* __restrict__ row_start) {
    __shared__ int cnt[BNODES];
    __shared__ int cur[BNODES];
    __shared__ int sm[256];
    int b = blockIdx.x, t = threadIdx.x;

    // tight output base = exclusive prefix of bucket_cnt over buckets < b
    sm[t] = (t < NBUCK) ? bucket_cnt[t] : 0;
    __syncthreads();
    for (int off = 1; off < 256; off <<= 1) {
        int v = (t >= off) ? sm[t - off] : 0;
        __syncthreads();
        sm[t] += v;
        __syncthreads();
    }
    int myCnt     = bucket_cnt[b];
    int tight_beg = sm[b] - myCnt;
    int beg_pad   = b * BSLOT;
    int end_pad   = beg_pad + myCnt;
    __syncthreads();                       // sm reused below

#pragma unroll
    for (int j = 0; j < 4; j++) cnt[t * 4 + j] = 0;
    __syncthreads();
    for (int e = beg_pad + t; e < end_pad; e += 256)
        atomicAdd(&cnt[packed[e] & (BNODES - 1)], 1);
    __syncthreads();
    int c0 = cnt[t * 4], c1 = cnt[t * 4 + 1], c2 = cnt[t * 4 + 2], c3 = cnt[t * 4 + 3];
    int tot = c0 + c1 + c2 + c3;
    sm[t] = tot;
    __syncthreads();
    for (int off = 1; off < 256; off <<= 1) {
        int v = (t >= off) ? sm[t - off] : 0;
        __syncthreads();
        sm[t] += v;
        __syncthreads();
    }
    int p0 = tight_beg + sm[t] - tot;
    int p1 = p0 + c0, p2 = p1 + c1, p3 = p2 + c2;
    cur[t * 4] = p0; cur[t * 4 + 1] = p1; cur[t * 4 + 2] = p2; cur[t * 4 + 3] = p3;
    int nodeb = b * BNODES + t * 4;
    int pv[4] = {p0, p1, p2, p3};
#pragma unroll
    for (int j = 0; j < 4; j++)
        if (nodeb + j <= N_NODES) row_start[nodeb + j] = pv[j];
    __syncthreads();
    for (int e = beg_pad + t; e < end_pad; e += 256) {
        int pk = packed[e];
        int pos = atomicAdd(&cur[pk & (BNODES - 1)], 1);
        csr_src[pos] = pk >> 10;
    }
}

// ---------------- K5: gather aggregation — one wave per node, 4 edges per iter ----------------
// (unchanged from round 1: fabric-BW-bound at ~4 TB/s, near its floor)
__global__ __launch_bounds__(256) void k_agg(const int* __restrict__ row_start,
                                             const int* __restrict__ csr_src,
                                             const float* __restrict__ s_src,
                                             const float* __restrict__ s_dst,
                                             const ushort* __restrict__ h,
                                             const float* __restrict__ bias,
                                             float* __restrict__ out) {
    const int n    = blockIdx.x * 4 + (threadIdx.x >> 6);   // 4 nodes per block, 1 wave each
    const int lane = threadIdx.x & 63;
    const int g    = lane >> 4;          // edge sub-group 0..3
    const int q    = lane & 15;          // channel quad: ch = q*8 .. q*8+7
    const int head = q >> 2;             // 32 ch per head / 8 ch per quad

    const float sdh = s_dst[n * HEADS + head];
    const int beg = row_start[n], end = row_start[n + 1];
    const uint4* __restrict__ hrow = reinterpret_cast<const uint4*>(h);   // 16 uint4 per node row

    float acc[8];
#pragma unroll
    for (int k = 0; k < 8; k++) acc[k] = 0.f;
    float sum_w = 0.f;

#pragma unroll 2
    for (int j = beg; j < end; j += 4) {
        int e = j + g;
        bool valid = e < end;
        int src = csr_src[valid ? e : end - 1];          // clamp keeps load safe
        float ss = s_src[src * HEADS + head];            // L2-resident table
        uint4 u = hrow[(size_t)src * (HID / 8) + q];     // 16B = 8 bf16 channels
        float a = ss + sdh;
        a = fmaxf(a, NEG_SLOPE * a);                     // leaky relu
        float wgt = valid ? __expf(a) : 0.f;
        sum_w += wgt;
        uint uv[4] = {u.x, u.y, u.z, u.w};
#pragma unroll
        for (int t = 0; t < 4; t++) {
            acc[2 * t]     = fmaf(wgt, __uint_as_float(uv[t] << 16),        acc[2 * t]);
            acc[2 * t + 1] = fmaf(wgt, __uint_as_float(uv[t] & 0xFFFF0000u), acc[2 * t + 1]);
        }
    }

    // reduce the 4 edge-groups (lanes differing in bits 4,5)
#pragma unroll
    for (int k = 0; k < 8; k++) {
        acc[k] += __shfl_xor(acc[k], 16);
        acc[k] += __shfl_xor(acc[k], 32);
    }
    sum_w += __shfl_xor(sum_w, 16);
    sum_w += __shfl_xor(sum_w, 32);

    if (g == 0) {
        float inv = 1.0f / (sum_w + 1e-16f);
        int ch = q * 8;
        float4 b0 = *reinterpret_cast<const float4*>(bias + ch);
        float4 b1 = *reinterpret_cast<const float4*>(bias + ch + 4);
        float4 o0, o1;
        o0.x = acc[0] * inv + b0.x; o0.y = acc[1] * inv + b0.y;
        o0.z = acc[2] * inv + b0.z; o0.w = acc[3] * inv + b0.w;
        o1.x = acc[4] * inv + b1.x; o1.y = acc[5] * inv + b1.y;
        o1.z = acc[6] * inv + b1.z; o1.w = acc[7] * inv + b1.w;
        *reinterpret_cast<float4*>(out + (size_t)n * HID + ch)     = o0;
        *reinterpret_cast<float4*>(out + (size_t)n * HID + ch + 4) = o1;
    }
}

extern "C" void kernel_launch(void* const* d_in, const int* in_sizes, int n_in,
                              void* d_out, int out_size, void* d_ws, size_t ws_size,
                              hipStream_t stream) {
    const float* x    = (const float*)d_in[0];
    const int*   ei   = (const int*)  d_in[1];
    const float* w    = (const float*)d_in[2];
    const float* att  = (const float*)d_in[3];
    const float* bias = (const float*)d_in[4];
    float* out = (float*)d_out;

    char* p = (char*)d_ws;
    float* s_src    = (float*)p;  p += (size_t)N_NODES * HEADS * 4;   // 1.6 MB
    float* s_dst    = (float*)p;  p += (size_t)N_NODES * HEADS * 4;   // 1.6 MB
    ushort* h       = (ushort*)p; p += (size_t)N_NODES * HID * 2;     // 25.6 MB (16B-aligned)
    int* csr_src    = (int*)p;    p += (size_t)N_EDGES * 4;           // 6.4 MB
    int* packed     = (int*)p;    p += (size_t)NBUCK * BSLOT * 4;     // 7.2 MB (padded buckets)
    int* row_start  = (int*)p;    p += (size_t)(N_NODES + 1) * 4;
    int* bucket_cnt = (int*)p;    p += (size_t)NBUCK * 4;

    k_gemm<<<(N_NODES + BM - 1) / BM, 256, 0, stream>>>(x, w, att, h, s_src, s_dst, bucket_cnt);
    k_scatter<<<NBLK, 256, 0, stream>>>(ei, bucket_cnt, packed);
    k_b2<<<NBUCK, 256, 0, stream>>>(packed, bucket_cnt, csr_src, row_start);
    k_agg<<<N_NODES / 4, 256, 0, stream>>>(row_start, csr_src, s_src, s_dst, h, bias, out);
}